// Round 6
// baseline (10054.008 us; speedup 1.0000x reference)
//
#include <hip/hip_runtime.h>
#include <stdint.h>

// ---------------------------------------------------------------------------
// RNN rollout. Phase 1: teacher-forced recurrence (cell only) + bulk batched
// psi. Phase 2: persistent cooperative kernel, 8 groups x 32 members.
// R6 = R3 kernel VERBATIM (proven to launch+validate at 7.97 ms) with ONE
// change: g = blockIdx>>5, m = blockIdx&31. Member m -> XCD m%8 for every
// group, so each XCD caches only 4 weight col-slices (~1 MB, L2-resident)
// instead of the full 7 MB set (R3's measured 15 MB/step L2 thrash).
// Sizes fixed: B=128, T=256, HOR=512, OBS=32, LAT=256, HID=1024.
// ---------------------------------------------------------------------------

#define BATCH 128
#define TTF   256
#define HOR   512
#define OBS   32
#define LAT   256
#define HID   1024

#define GROUPS  8
#define MEMBERS 32
#define ARBLOCKS (GROUPS * MEMBERS)
#define ARTHREADS 128

typedef __attribute__((ext_vector_type(8))) short short8;
typedef __attribute__((ext_vector_type(4))) float floatx4;

// ---- workspace layout (bytes) ----
#define OFF_WB1   ((size_t)0)                          // 1024x256 bf16 ([col][k])
#define OFF_WB2   (OFF_WB1 + (size_t)HID*LAT*2)        // 1024x1024 bf16
#define OFF_WB3   (OFF_WB2 + (size_t)HID*HID*2)
#define OFF_WB4   (OFF_WB3 + (size_t)HID*HID*2)
#define OFF_WB5   (OFF_WB4 + (size_t)HID*HID*2)        // 32x1024 bf16
#define OFF_CB    (OFF_WB5 + (size_t)OBS*HID*2)        // 256 f32 (b_ih+b_hh)
#define OFF_WHH2  (OFF_CB + (size_t)LAT*4)             // 64x256 uint2 packed W_hh^T
#define OFF_WIH2  (OFF_WHH2 + (size_t)64*256*8)        // 8x256 uint2 packed W_ih^T
#define OFF_ZF    (OFF_WIH2 + (size_t)8*256*8)         // 128x256 f32
#define OFF_Z     (OFF_ZF + (size_t)BATCH*LAT*4)       // 32768x256 bf16
#define OFF_WBC   (OFF_Z + (size_t)BATCH*TTF*LAT*2)    // 256x288 bf16 cell matrix
#define OFF_HB    (OFF_WBC + (size_t)LAT*288*2)        // 8 x 4 x 16x1024 bf16
#define OFF_ZB    (OFF_HB + (size_t)GROUPS*4*16*HID*2) // 8 x 2 x 16x256 bf16
#define OFF_CTR   (OFF_ZB + (size_t)GROUPS*2*16*LAT*2) // 8 x 128B counters
#define OFF_END   (OFF_CTR + (size_t)GROUPS*128)

__device__ __forceinline__ uint16_t f2bf(float f) {
    uint32_t u = __float_as_uint(f);
    u += 0x7fffu + ((u >> 16) & 1u);   // RNE
    return (uint16_t)(u >> 16);
}
__device__ __forceinline__ float bflo(uint32_t u) { return __uint_as_float(u << 16); }
__device__ __forceinline__ float bfhi(uint32_t u) { return __uint_as_float(u & 0xffff0000u); }

__device__ __forceinline__ float fast_tanh(float x) {
    float ax = fabsf(x);
    float e  = __expf(-2.f * ax);
    float r  = (1.f - e) / (1.f + e);
    return copysignf(r, x);
}

__device__ __forceinline__ int hswz(int row, int col) {
    return row * 1024 + ((((col >> 3) ^ (row & 7)) << 3) | (col & 7));
}

// --- MALL-coherent exchange primitives (sc0 sc1 bypass; no L2 inv) ---
union V16 { short8 s; uint64_t u[2]; };

__device__ __forceinline__ short8 aload16(const uint16_t* p) {
    const uint64_t* q = (const uint64_t*)p;
    V16 v;
    v.u[0] = __hip_atomic_load(q + 0, __ATOMIC_RELAXED, __HIP_MEMORY_SCOPE_AGENT);
    v.u[1] = __hip_atomic_load(q + 1, __ATOMIC_RELAXED, __HIP_MEMORY_SCOPE_AGENT);
    return v.s;
}
__device__ __forceinline__ void astore2(uint16_t* p, uint16_t v) {
    __hip_atomic_store(p, v, __ATOMIC_RELAXED, __HIP_MEMORY_SCOPE_AGENT);
}

// group barrier, fence-free: __syncthreads drains vmcnt(0) before s_barrier,
// so all (cache-bypassing) stores are at MALL before the flag add; the flag
// itself is a MALL atomic; consumers' loads also bypass caches -> no
// buffer_inv needed -> weights stay L2-resident.
__device__ __forceinline__ void gbar(unsigned* ctr, unsigned target) {
    __syncthreads();
    if (threadIdx.x == 0) {
        __hip_atomic_fetch_add(ctr, 1u, __ATOMIC_RELAXED, __HIP_MEMORY_SCOPE_AGENT);
        while (__hip_atomic_load(ctr, __ATOMIC_RELAXED, __HIP_MEMORY_SCOPE_AGENT) < target) {}
    }
    __syncthreads();
}

// ---------------------------------------------------------------------------
// K0 helpers
// ---------------------------------------------------------------------------
__global__ void k_cvt(const float* __restrict__ s, uint16_t* __restrict__ d, int n) {
    int i = blockIdx.x * 256 + threadIdx.x;
    if (i < n) d[i] = f2bf(s[i]);
}

__global__ void k_cb(const float* __restrict__ a, const float* __restrict__ b,
                     float* __restrict__ c) {
    int j = threadIdx.x;
    c[j] = a[j] + b[j];
}

__global__ void k_pack(const float* __restrict__ w, uint2* __restrict__ dst, int klen) {
    int k4 = blockIdx.x, j = threadIdx.x;
    int k = k4 * 4;
    uint32_t a = f2bf(w[(size_t)j * klen + k + 0]);
    uint32_t b = f2bf(w[(size_t)j * klen + k + 1]);
    uint32_t c = f2bf(w[(size_t)j * klen + k + 2]);
    uint32_t d = f2bf(w[(size_t)j * klen + k + 3]);
    uint2 r; r.x = a | (b << 16); r.y = c | (d << 16);
    dst[k4 * 256 + j] = r;
}

__global__ void k_packc(const float* __restrict__ whh, const float* __restrict__ wih,
                        uint16_t* __restrict__ wbc) {
    int col = blockIdx.x;
    for (int k = threadIdx.x; k < 288; k += 256) {
        float v = (k < 256) ? whh[(size_t)col * 256 + k] : wih[(size_t)col * 32 + (k - 256)];
        wbc[(size_t)col * 288 + k] = f2bf(v);
    }
}

// ---------------------------------------------------------------------------
// K1: teacher-forced recurrence. 128 blocks x 256 threads.
// ---------------------------------------------------------------------------
__global__ __launch_bounds__(256) void k_rnn_tf(
    const float* __restrict__ y, const uint2* __restrict__ whh2,
    const uint2* __restrict__ wih2, const float* __restrict__ cb,
    uint16_t* __restrict__ Zg, float* __restrict__ zfinal)
{
    __shared__ alignas(16) float zl[LAT];
    __shared__ alignas(16) float ys[OBS];
    int j = threadIdx.x, b = blockIdx.x;
    zl[j] = 0.f;
    __syncthreads();
    const float4* z4 = (const float4*)zl;
    const float4* y4 = (const float4*)ys;
    for (int t = 0; t < TTF; t++) {
        if (j < OBS) ys[j] = y[(size_t)b * (TTF * OBS) + t * OBS + j];
        Zg[((size_t)b * TTF + t) * LAT + j] = f2bf(zl[j]);
        __syncthreads();
        float acc = cb[j];
        #pragma unroll 8
        for (int k4 = 0; k4 < 64; k4++) {
            uint2 wv = whh2[k4 * 256 + j];
            float4 zq = z4[k4];
            acc += bflo(wv.x) * zq.x + bfhi(wv.x) * zq.y
                 + bflo(wv.y) * zq.z + bfhi(wv.y) * zq.w;
        }
        #pragma unroll
        for (int k4 = 0; k4 < 8; k4++) {
            uint2 wv = wih2[k4 * 256 + j];
            float4 yq = y4[k4];
            acc += bflo(wv.x) * yq.x + bfhi(wv.x) * yq.y
                 + bflo(wv.y) * yq.z + bfhi(wv.y) * yq.w;
        }
        __syncthreads();
        zl[j] = fast_tanh(acc);
    }
    __syncthreads();
    zfinal[(size_t)b * LAT + j] = zl[j];
}

// ---------------------------------------------------------------------------
// K2: bulk psi over all 32768 phase-1 states. 1024 blocks x 32 rows, 512 thr.
// ---------------------------------------------------------------------------
__global__ __launch_bounds__(512) void k_psi_bulk(
    const uint16_t* __restrict__ Zg,
    const uint16_t* __restrict__ wb1, const uint16_t* __restrict__ wb2,
    const uint16_t* __restrict__ wb3, const uint16_t* __restrict__ wb4,
    const uint16_t* __restrict__ wb5,
    const float* __restrict__ b1, const float* __restrict__ b2,
    const float* __restrict__ b3, const float* __restrict__ b4,
    const float* __restrict__ b5, float* __restrict__ out)
{
    __shared__ uint16_t hbuf[32 * 1024];   // 64 KB, swizzled
    int tid = threadIdx.x;
    int w = tid >> 6, L = tid & 63, lm = L & 15, q = L >> 4;
    int rb = blockIdx.x * 32;
    int colbase = w * 128;
    floatx4 acc[2][8];
    const floatx4 zero = {0.f, 0.f, 0.f, 0.f};

    #pragma unroll
    for (int mt = 0; mt < 2; mt++)
        #pragma unroll
        for (int nt = 0; nt < 8; nt++) acc[mt][nt] = zero;
    for (int kc = 0; kc < 8; kc++) {
        short8 a0 = *(const short8*)(Zg + (size_t)(rb + lm) * LAT + kc * 32 + q * 8);
        short8 a1 = *(const short8*)(Zg + (size_t)(rb + 16 + lm) * LAT + kc * 32 + q * 8);
        #pragma unroll
        for (int nt = 0; nt < 8; nt++) {
            int n = colbase + nt * 16 + lm;
            short8 bf = *(const short8*)(wb1 + (size_t)n * LAT + kc * 32 + q * 8);
            acc[0][nt] = __builtin_amdgcn_mfma_f32_16x16x32_bf16(a0, bf, acc[0][nt], 0, 0, 0);
            acc[1][nt] = __builtin_amdgcn_mfma_f32_16x16x32_bf16(a1, bf, acc[1][nt], 0, 0, 0);
        }
    }
    #pragma unroll
    for (int mt = 0; mt < 2; mt++)
        #pragma unroll
        for (int nt = 0; nt < 8; nt++) {
            int col = colbase + nt * 16 + lm;
            float bias = b1[col];
            #pragma unroll
            for (int i = 0; i < 4; i++) {
                int row = mt * 16 + q * 4 + i;
                hbuf[hswz(row, col)] = f2bf(fmaxf(acc[mt][nt][i] + bias, 0.f));
            }
        }
    __syncthreads();

    const uint16_t* wbs[3] = {wb2, wb3, wb4};
    const float*    bbs[3] = {b2, b3, b4};
    for (int ll = 0; ll < 3; ll++) {
        const uint16_t* wb = wbs[ll];
        const float* bb = bbs[ll];
        #pragma unroll
        for (int mt = 0; mt < 2; mt++)
            #pragma unroll
            for (int nt = 0; nt < 8; nt++) acc[mt][nt] = zero;
        for (int kc = 0; kc < 32; kc++) {
            int g = ((kc * 4 + q) ^ (lm & 7)) << 3;
            short8 a0 = *(const short8*)(hbuf + lm * 1024 + g);
            short8 a1 = *(const short8*)(hbuf + (16 + lm) * 1024 + g);
            #pragma unroll
            for (int nt = 0; nt < 8; nt++) {
                int n = colbase + nt * 16 + lm;
                short8 bf = *(const short8*)(wb + (size_t)n * HID + kc * 32 + q * 8);
                acc[0][nt] = __builtin_amdgcn_mfma_f32_16x16x32_bf16(a0, bf, acc[0][nt], 0, 0, 0);
                acc[1][nt] = __builtin_amdgcn_mfma_f32_16x16x32_bf16(a1, bf, acc[1][nt], 0, 0, 0);
            }
        }
        __syncthreads();
        #pragma unroll
        for (int mt = 0; mt < 2; mt++)
            #pragma unroll
            for (int nt = 0; nt < 8; nt++) {
                int col = colbase + nt * 16 + lm;
                float bias = bb[col];
                #pragma unroll
                for (int i = 0; i < 4; i++) {
                    int row = mt * 16 + q * 4 + i;
                    hbuf[hswz(row, col)] = f2bf(fmaxf(acc[mt][nt][i] + bias, 0.f));
                }
            }
        __syncthreads();
    }

    if (w < 4) {
        int mt = w >> 1;
        int nb = (w & 1) * 16;
        floatx4 a5 = zero;
        for (int kc = 0; kc < 32; kc++) {
            int g = ((kc * 4 + q) ^ (lm & 7)) << 3;
            short8 a = *(const short8*)(hbuf + (mt * 16 + lm) * 1024 + g);
            short8 bf = *(const short8*)(wb5 + (size_t)(nb + lm) * HID + kc * 32 + q * 8);
            a5 = __builtin_amdgcn_mfma_f32_16x16x32_bf16(a, bf, a5, 0, 0, 0);
        }
        int col = nb + lm;
        float bias = b5[col];
        #pragma unroll
        for (int i = 0; i < 4; i++) {
            int row = mt * 16 + q * 4 + i;
            int r = rb + row;
            int bb_ = r >> 8, tt = r & 255;
            out[(size_t)bb_ * (HOR * OBS) + tt * OBS + col] = a5[i] + bias;
        }
    }
}

// ---------------------------------------------------------------------------
// K3 v6 (= v3 + XCD remap): persistent cooperative AR. 8 groups x 32 members,
// 128 threads. g = blockIdx>>5, m = blockIdx&31 (member m -> XCD m%8 for all
// groups; each XCD caches 4 col-slices ~1 MB). Exchange via MALL atomics;
// weights via normal cached loads. W2 slice LDS-resident.
// ---------------------------------------------------------------------------
__global__ __launch_bounds__(ARTHREADS) void k_ar2(
    const float* __restrict__ zfinal,
    const uint16_t* __restrict__ wb1, const uint16_t* __restrict__ wb2,
    const uint16_t* __restrict__ wb3, const uint16_t* __restrict__ wb4,
    const uint16_t* __restrict__ wb5, const uint16_t* __restrict__ wbc,
    const float* __restrict__ b1g, const float* __restrict__ b2g,
    const float* __restrict__ b3g, const float* __restrict__ b4g,
    const float* __restrict__ b5g, const float* __restrict__ cb,
    uint16_t* __restrict__ hb_all, uint16_t* __restrict__ zb_all,
    unsigned* __restrict__ ctr_all, float* __restrict__ out)
{
    __shared__ alignas(16) uint16_t w2l[31 * 1024];   // 62 KB
    __shared__ alignas(16) uint16_t yscr[16 * 32];    // 1 KB
    const int tid = threadIdx.x;
    const int g = blockIdx.x >> 5, m = blockIdx.x & 31;   // R6: member m -> XCD m%8
    const int w = tid >> 6, L = tid & 63, lm = L & 15, q = L >> 4;
    const int colbase = m * 32;
    const int cl = w * 16 + lm;
    const int rb = g * 16;
    uint16_t* hb = hb_all + (size_t)g * (4 * 16 * HID);
    uint16_t* zb = zb_all + (size_t)g * (2 * 16 * LAT);
    unsigned* ctr = ctr_all + g * 32;
    const floatx4 zero = {0.f, 0.f, 0.f, 0.f};

    // preload W2 slice into LDS (normal cached loads)
    for (int idx = tid; idx < 31 * 32 * 4; idx += ARTHREADS) {
        int kc = idx >> 7, r = idx & 127, c = r >> 2, qq = r & 3;
        *(short8*)(w2l + kc * 1024 + c * 32 + qq * 8) =
            *(const short8*)(wb2 + (size_t)(colbase + c) * HID + kc * 32 + qq * 8);
    }
    // member 0: zfinal -> z parity 0 (MALL stores)
    if (m == 0) {
        for (int idx = tid; idx < 16 * 256; idx += ARTHREADS) {
            int r = idx >> 8, c = idx & 255;
            astore2(zb + r * 256 + c, f2bf(zfinal[(size_t)(rb + r) * LAT + c]));
        }
    }
    unsigned tgt = 0;
    gbar(ctr, tgt += MEMBERS);

    uint16_t* h1 = hb;
    uint16_t* h2 = hb + 16 * HID;
    uint16_t* h3 = hb + 2 * 16 * HID;
    uint16_t* h4 = hb + 3 * 16 * HID;

    #pragma unroll 1
    for (int t = 0; t < HOR - TTF; t++) {
        uint16_t* zcur = zb + (t & 1) * (16 * 256);
        uint16_t* znext = zb + ((t + 1) & 1) * (16 * 256);

        // ---- L1: h1 = relu(z @ W1s + b1)
        {
            floatx4 acc = zero;
            const uint16_t* ab = zcur + lm * 256 + q * 8;
            const uint16_t* bb = wb1 + (size_t)(colbase + cl) * LAT + q * 8;
            #pragma unroll
            for (int kc = 0; kc < 8; kc++) {
                short8 a = aload16(ab + kc * 32);
                short8 b = *(const short8*)(bb + kc * 32);
                acc = __builtin_amdgcn_mfma_f32_16x16x32_bf16(a, b, acc, 0, 0, 0);
            }
            int col = colbase + cl;
            float bias = b1g[col];
            #pragma unroll
            for (int i = 0; i < 4; i++)
                astore2(h1 + (q * 4 + i) * HID + col, f2bf(fmaxf(acc[i] + bias, 0.f)));
        }
        gbar(ctr, tgt += MEMBERS);

        // ---- L2: LDS-resident W2 (kc 0..30) + streamed tail
        {
            floatx4 acc = zero;
            const uint16_t* ab = h1 + lm * HID + q * 8;
            const uint16_t* bl = w2l + cl * 32 + q * 8;
            #pragma unroll 8
            for (int kc = 0; kc < 31; kc++) {
                short8 a = aload16(ab + kc * 32);
                short8 b = *(const short8*)(bl + kc * 1024);
                acc = __builtin_amdgcn_mfma_f32_16x16x32_bf16(a, b, acc, 0, 0, 0);
            }
            {
                short8 a = aload16(ab + 31 * 32);
                short8 b = *(const short8*)(wb2 + (size_t)(colbase + cl) * HID + 992 + q * 8);
                acc = __builtin_amdgcn_mfma_f32_16x16x32_bf16(a, b, acc, 0, 0, 0);
            }
            int col = colbase + cl;
            float bias = b2g[col];
            #pragma unroll
            for (int i = 0; i < 4; i++)
                astore2(h2 + (q * 4 + i) * HID + col, f2bf(fmaxf(acc[i] + bias, 0.f)));
        }
        gbar(ctr, tgt += MEMBERS);

        // ---- L3
        {
            floatx4 acc = zero;
            const uint16_t* ab = h2 + lm * HID + q * 8;
            const uint16_t* bb = wb3 + (size_t)(colbase + cl) * HID + q * 8;
            #pragma unroll 8
            for (int kc = 0; kc < 32; kc++) {
                short8 a = aload16(ab + kc * 32);
                short8 b = *(const short8*)(bb + kc * 32);
                acc = __builtin_amdgcn_mfma_f32_16x16x32_bf16(a, b, acc, 0, 0, 0);
            }
            int col = colbase + cl;
            float bias = b3g[col];
            #pragma unroll
            for (int i = 0; i < 4; i++)
                astore2(h3 + (q * 4 + i) * HID + col, f2bf(fmaxf(acc[i] + bias, 0.f)));
        }
        gbar(ctr, tgt += MEMBERS);

        // ---- L4
        {
            floatx4 acc = zero;
            const uint16_t* ab = h3 + lm * HID + q * 8;
            const uint16_t* bb = wb4 + (size_t)(colbase + cl) * HID + q * 8;
            #pragma unroll 8
            for (int kc = 0; kc < 32; kc++) {
                short8 a = aload16(ab + kc * 32);
                short8 b = *(const short8*)(bb + kc * 32);
                acc = __builtin_amdgcn_mfma_f32_16x16x32_bf16(a, b, acc, 0, 0, 0);
            }
            int col = colbase + cl;
            float bias = b4g[col];
            #pragma unroll
            for (int i = 0; i < 4; i++)
                astore2(h4 + (q * 4 + i) * HID + col, f2bf(fmaxf(acc[i] + bias, 0.f)));
        }
        gbar(ctr, tgt += MEMBERS);

        // ---- stage 5 (members 0..7): L5 redundant + cell slice
        if (m < 8) {
            floatx4 a5 = zero;
            const uint16_t* ab = h4 + lm * HID + q * 8;
            const uint16_t* bb = wb5 + (size_t)cl * HID + q * 8;
            #pragma unroll 8
            for (int kc = 0; kc < 32; kc++) {
                short8 a = aload16(ab + kc * 32);
                short8 b = *(const short8*)(bb + kc * 32);
                a5 = __builtin_amdgcn_mfma_f32_16x16x32_bf16(a, b, a5, 0, 0, 0);
            }
            float bias = b5g[cl];
            float vout[4];
            #pragma unroll
            for (int i = 0; i < 4; i++) {
                float v = a5[i] + bias;
                vout[i] = v;
                yscr[(q * 4 + i) * 32 + cl] = f2bf(v);
            }
            if (m == 0) {
                #pragma unroll
                for (int i = 0; i < 4; i++)
                    out[(size_t)(rb + q * 4 + i) * (HOR * OBS) + (TTF + t) * OBS + cl] = vout[i];
            }
            __syncthreads();
            floatx4 cc = zero;
            int ccol = m * 32 + cl;
            const uint16_t* bb2 = wbc + (size_t)ccol * 288 + q * 8;
            #pragma unroll
            for (int kc = 0; kc < 9; kc++) {
                short8 a;
                if (kc < 8) a = aload16(zcur + lm * 256 + kc * 32 + q * 8);
                else        a = *(const short8*)(yscr + lm * 32 + q * 8);
                short8 b = *(const short8*)(bb2 + kc * 32);
                cc = __builtin_amdgcn_mfma_f32_16x16x32_bf16(a, b, cc, 0, 0, 0);
            }
            float cbv = cb[ccol];
            #pragma unroll
            for (int i = 0; i < 4; i++)
                astore2(znext + (q * 4 + i) * 256 + ccol, f2bf(fast_tanh(cc[i] + cbv)));
        }
        gbar(ctr, tgt += MEMBERS);
    }
}

// ---------------------------------------------------------------------------
extern "C" void kernel_launch(void* const* d_in, const int* in_sizes, int n_in,
                              void* d_out, int out_size, void* d_ws, size_t ws_size,
                              hipStream_t stream) {
    (void)in_sizes; (void)n_in; (void)out_size; (void)ws_size;
    const float* y    = (const float*)d_in[0];
    const float* W_ih = (const float*)d_in[2];
    const float* W_hh = (const float*)d_in[3];
    const float* b_ih = (const float*)d_in[4];
    const float* b_hh = (const float*)d_in[5];
    const float* W1   = (const float*)d_in[6];
    const float* b1   = (const float*)d_in[7];
    const float* W2   = (const float*)d_in[8];
    const float* b2   = (const float*)d_in[9];
    const float* W3   = (const float*)d_in[10];
    const float* b3   = (const float*)d_in[11];
    const float* W4   = (const float*)d_in[12];
    const float* b4   = (const float*)d_in[13];
    const float* W5   = (const float*)d_in[14];
    const float* b5   = (const float*)d_in[15];
    float* out = (float*)d_out;
    char* ws = (char*)d_ws;

    uint16_t* WB1  = (uint16_t*)(ws + OFF_WB1);
    uint16_t* WB2  = (uint16_t*)(ws + OFF_WB2);
    uint16_t* WB3  = (uint16_t*)(ws + OFF_WB3);
    uint16_t* WB4  = (uint16_t*)(ws + OFF_WB4);
    uint16_t* WB5  = (uint16_t*)(ws + OFF_WB5);
    float*    CB   = (float*)(ws + OFF_CB);
    uint2*    WHH2 = (uint2*)(ws + OFF_WHH2);
    uint2*    WIH2 = (uint2*)(ws + OFF_WIH2);
    float*    ZF   = (float*)(ws + OFF_ZF);
    uint16_t* Zbuf = (uint16_t*)(ws + OFF_Z);
    uint16_t* WBC  = (uint16_t*)(ws + OFF_WBC);
    uint16_t* HB   = (uint16_t*)(ws + OFF_HB);
    uint16_t* ZB   = (uint16_t*)(ws + OFF_ZB);
    unsigned* CTR  = (unsigned*)(ws + OFF_CTR);

    k_cvt<<<(HID*LAT + 255) / 256, 256, 0, stream>>>(W1, WB1, HID * LAT);
    k_cvt<<<(HID*HID + 255) / 256, 256, 0, stream>>>(W2, WB2, HID * HID);
    k_cvt<<<(HID*HID + 255) / 256, 256, 0, stream>>>(W3, WB3, HID * HID);
    k_cvt<<<(HID*HID + 255) / 256, 256, 0, stream>>>(W4, WB4, HID * HID);
    k_cvt<<<(OBS*HID + 255) / 256, 256, 0, stream>>>(W5, WB5, OBS * HID);
    k_cb<<<1, 256, 0, stream>>>(b_ih, b_hh, CB);
    k_pack<<<64, 256, 0, stream>>>(W_hh, WHH2, LAT);
    k_pack<<<8, 256, 0, stream>>>(W_ih, WIH2, OBS);
    k_packc<<<256, 256, 0, stream>>>(W_hh, W_ih, WBC);
    hipMemsetAsync(CTR, 0, GROUPS * 128, stream);

    k_rnn_tf<<<BATCH, 256, 0, stream>>>(y, WHH2, WIH2, CB, Zbuf, ZF);

    k_psi_bulk<<<(BATCH * TTF) / 32, 512, 0, stream>>>(
        Zbuf, WB1, WB2, WB3, WB4, WB5, b1, b2, b3, b4, b5, out);

    void* args[] = {
        (void*)&ZF, (void*)&WB1, (void*)&WB2, (void*)&WB3, (void*)&WB4,
        (void*)&WB5, (void*)&WBC, (void*)&b1, (void*)&b2, (void*)&b3,
        (void*)&b4, (void*)&b5, (void*)&CB, (void*)&HB, (void*)&ZB,
        (void*)&CTR, (void*)&out
    };
    hipLaunchCooperativeKernel((const void*)k_ar2, dim3(ARBLOCKS), dim3(ARTHREADS),
                               args, 0, stream);
}

// Round 8
// 7996.619 us; speedup vs baseline: 1.2573x; 1.2573x over previous
//
#include <hip/hip_runtime.h>
#include <stdint.h>

// ---------------------------------------------------------------------------
// RNN rollout. Phase 1: teacher-forced recurrence (cell only) + bulk batched
// psi. Phase 2: persistent AR kernel, 8 groups x 32 members, member m -> XCD
// m%8 (weights L2-resident, proven R6). R8: (a) cooperative-launch return is
// CHECKED with plain-launch fallback (R4/R5/R7 all died on silent rejection);
// (b) exchange tiles (h 32KB, z 8KB) are stored pre-swizzled at MALL and
// bulk-DMA'd into LDS via global_load_lds(16B, sc0|sc1) -- ~1 RTT/stage vs
// R6's compiler-serialized atomic loads. No atomic loads in the step loop.
// Sizes fixed: B=128, T=256, HOR=512, OBS=32, LAT=256, HID=1024.
// ---------------------------------------------------------------------------

#define BATCH 128
#define TTF   256
#define HOR   512
#define OBS   32
#define LAT   256
#define HID   1024

#define GROUPS  8
#define MEMBERS 32
#define ARBLOCKS (GROUPS * MEMBERS)
#define ARTHREADS 128

typedef __attribute__((ext_vector_type(8))) short short8;
typedef __attribute__((ext_vector_type(4))) float floatx4;

// ---- workspace layout (bytes) ----
#define OFF_WB1   ((size_t)0)                          // 1024x256 bf16 ([col][k])
#define OFF_WB2   (OFF_WB1 + (size_t)HID*LAT*2)        // 1024x1024 bf16
#define OFF_WB3   (OFF_WB2 + (size_t)HID*HID*2)
#define OFF_WB4   (OFF_WB3 + (size_t)HID*HID*2)
#define OFF_WB5   (OFF_WB4 + (size_t)HID*HID*2)        // 32x1024 bf16
#define OFF_CB    (OFF_WB5 + (size_t)OBS*HID*2)        // 256 f32 (b_ih+b_hh)
#define OFF_WHH2  (OFF_CB + (size_t)LAT*4)             // 64x256 uint2 packed W_hh^T
#define OFF_WIH2  (OFF_WHH2 + (size_t)64*256*8)        // 8x256 uint2 packed W_ih^T
#define OFF_ZF    (OFF_WIH2 + (size_t)8*256*8)         // 128x256 f32
#define OFF_Z     (OFF_ZF + (size_t)BATCH*LAT*4)       // 32768x256 bf16
#define OFF_WBC   (OFF_Z + (size_t)BATCH*TTF*LAT*2)    // 256x288 bf16 cell matrix
#define OFF_HB    (OFF_WBC + (size_t)LAT*288*2)        // 8 x 4 x 16x1024 bf16
#define OFF_ZB    (OFF_HB + (size_t)GROUPS*4*16*HID*2) // 8 x 2 x 16x256 bf16
#define OFF_CTR   (OFF_ZB + (size_t)GROUPS*2*16*LAT*2) // 8 x 128B counters
#define OFF_END   (OFF_CTR + (size_t)GROUPS*128)

__device__ __forceinline__ uint16_t f2bf(float f) {
    uint32_t u = __float_as_uint(f);
    u += 0x7fffu + ((u >> 16) & 1u);   // RNE
    return (uint16_t)(u >> 16);
}
__device__ __forceinline__ float bflo(uint32_t u) { return __uint_as_float(u << 16); }
__device__ __forceinline__ float bfhi(uint32_t u) { return __uint_as_float(u & 0xffff0000u); }

__device__ __forceinline__ float fast_tanh(float x) {
    float ax = fabsf(x);
    float e  = __expf(-2.f * ax);
    float r  = (1.f - e) / (1.f + e);
    return copysignf(r, x);
}

// XOR-granule swizzles (16B granule index ^ low bits of row). Producers store
// swizzled at MALL; the verbatim DMA lands swizzled in LDS; readers XOR back.
__device__ __forceinline__ int hswz(int row, int col) {   // h: stride 1024
    return row * 1024 + ((((col >> 3) ^ (row & 7)) << 3) | (col & 7));
}
__device__ __forceinline__ int zswz(int row, int col) {   // z: stride 256
    return row * 256 + ((((col >> 3) ^ (row & 7)) << 3) | (col & 7));
}

// --- MALL-coherent store (relaxed agent atomic = sc0 sc1, proven R3/R6) ---
__device__ __forceinline__ void astore2(uint16_t* p, uint16_t v) {
    __hip_atomic_store(p, v, __ATOMIC_RELAXED, __HIP_MEMORY_SCOPE_AGENT);
}

// async DMA global->LDS, 16 B/lane, aux=0x11 (CPol SC0|SC1): reads at MALL
// (coherent with astore2 writers), does not allocate into L1/L2.
typedef const __attribute__((address_space(1))) void* gas_t;
typedef __attribute__((address_space(3))) void* las_t;
__device__ __forceinline__ void gl_lds16(const void* g, void* l) {
    __builtin_amdgcn_global_load_lds((gas_t)g, (las_t)l, 16, 0, 0x11);
}

// 32 KB h tile MALL -> LDS: per wave 16 issues x 1 KB, all in flight.
__device__ __forceinline__ void stage_h(const uint16_t* src, uint16_t* dst,
                                        int w, int L) {
    const char* gp = (const char*)src + w * 16384 + L * 16;
    char* lp = (char*)dst + w * 16384;
    #pragma unroll
    for (int i = 0; i < 16; i++)
        gl_lds16(gp + i * 1024, lp + i * 1024);
}
// 8 KB z tile MALL -> LDS: per wave 4 issues x 1 KB.
__device__ __forceinline__ void stage_z(const uint16_t* src, uint16_t* dst,
                                        int w, int L) {
    const char* gp = (const char*)src + w * 1024 + L * 16;
    char* lp = (char*)dst + w * 1024;
    #pragma unroll
    for (int i = 0; i < 4; i++)
        gl_lds16(gp + i * 2048, lp + i * 2048);
}

// group barrier, fence-free (proven R3/R6): __syncthreads drains vmcnt(0)
// (covers astore2 AND the LDS-DMA), flag is a MALL atomic, consumer reads
// bypass caches -> no buffer_inv -> weights stay L2-resident.
__device__ __forceinline__ void gbar(unsigned* ctr, unsigned target) {
    __syncthreads();
    if (threadIdx.x == 0) {
        __hip_atomic_fetch_add(ctr, 1u, __ATOMIC_RELAXED, __HIP_MEMORY_SCOPE_AGENT);
        while (__hip_atomic_load(ctr, __ATOMIC_RELAXED, __HIP_MEMORY_SCOPE_AGENT) < target) {}
    }
    __syncthreads();
}

// ---------------------------------------------------------------------------
// K0 helpers
// ---------------------------------------------------------------------------
__global__ void k_cvt(const float* __restrict__ s, uint16_t* __restrict__ d, int n) {
    int i = blockIdx.x * 256 + threadIdx.x;
    if (i < n) d[i] = f2bf(s[i]);
}

__global__ void k_cb(const float* __restrict__ a, const float* __restrict__ b,
                     float* __restrict__ c) {
    int j = threadIdx.x;
    c[j] = a[j] + b[j];
}

__global__ void k_pack(const float* __restrict__ w, uint2* __restrict__ dst, int klen) {
    int k4 = blockIdx.x, j = threadIdx.x;
    int k = k4 * 4;
    uint32_t a = f2bf(w[(size_t)j * klen + k + 0]);
    uint32_t b = f2bf(w[(size_t)j * klen + k + 1]);
    uint32_t c = f2bf(w[(size_t)j * klen + k + 2]);
    uint32_t d = f2bf(w[(size_t)j * klen + k + 3]);
    uint2 r; r.x = a | (b << 16); r.y = c | (d << 16);
    dst[k4 * 256 + j] = r;
}

__global__ void k_packc(const float* __restrict__ whh, const float* __restrict__ wih,
                        uint16_t* __restrict__ wbc) {
    int col = blockIdx.x;
    for (int k = threadIdx.x; k < 288; k += 256) {
        float v = (k < 256) ? whh[(size_t)col * 256 + k] : wih[(size_t)col * 32 + (k - 256)];
        wbc[(size_t)col * 288 + k] = f2bf(v);
    }
}

// ---------------------------------------------------------------------------
// K1: teacher-forced recurrence. 128 blocks x 256 threads.
// ---------------------------------------------------------------------------
__global__ __launch_bounds__(256) void k_rnn_tf(
    const float* __restrict__ y, const uint2* __restrict__ whh2,
    const uint2* __restrict__ wih2, const float* __restrict__ cb,
    uint16_t* __restrict__ Zg, float* __restrict__ zfinal)
{
    __shared__ alignas(16) float zl[LAT];
    __shared__ alignas(16) float ys[OBS];
    int j = threadIdx.x, b = blockIdx.x;
    zl[j] = 0.f;
    __syncthreads();
    const float4* z4 = (const float4*)zl;
    const float4* y4 = (const float4*)ys;
    for (int t = 0; t < TTF; t++) {
        if (j < OBS) ys[j] = y[(size_t)b * (TTF * OBS) + t * OBS + j];
        Zg[((size_t)b * TTF + t) * LAT + j] = f2bf(zl[j]);
        __syncthreads();
        float acc = cb[j];
        #pragma unroll 8
        for (int k4 = 0; k4 < 64; k4++) {
            uint2 wv = whh2[k4 * 256 + j];
            float4 zq = z4[k4];
            acc += bflo(wv.x) * zq.x + bfhi(wv.x) * zq.y
                 + bflo(wv.y) * zq.z + bfhi(wv.y) * zq.w;
        }
        #pragma unroll
        for (int k4 = 0; k4 < 8; k4++) {
            uint2 wv = wih2[k4 * 256 + j];
            float4 yq = y4[k4];
            acc += bflo(wv.x) * yq.x + bfhi(wv.x) * yq.y
                 + bflo(wv.y) * yq.z + bfhi(wv.y) * yq.w;
        }
        __syncthreads();
        zl[j] = fast_tanh(acc);
    }
    __syncthreads();
    zfinal[(size_t)b * LAT + j] = zl[j];
}

// ---------------------------------------------------------------------------
// K2: bulk psi over all 32768 phase-1 states. 1024 blocks x 32 rows, 512 thr.
// ---------------------------------------------------------------------------
__global__ __launch_bounds__(512) void k_psi_bulk(
    const uint16_t* __restrict__ Zg,
    const uint16_t* __restrict__ wb1, const uint16_t* __restrict__ wb2,
    const uint16_t* __restrict__ wb3, const uint16_t* __restrict__ wb4,
    const uint16_t* __restrict__ wb5,
    const float* __restrict__ b1, const float* __restrict__ b2,
    const float* __restrict__ b3, const float* __restrict__ b4,
    const float* __restrict__ b5, float* __restrict__ out)
{
    __shared__ uint16_t hbuf[32 * 1024];   // 64 KB, swizzled
    int tid = threadIdx.x;
    int w = tid >> 6, L = tid & 63, lm = L & 15, q = L >> 4;
    int rb = blockIdx.x * 32;
    int colbase = w * 128;
    floatx4 acc[2][8];
    const floatx4 zero = {0.f, 0.f, 0.f, 0.f};

    #pragma unroll
    for (int mt = 0; mt < 2; mt++)
        #pragma unroll
        for (int nt = 0; nt < 8; nt++) acc[mt][nt] = zero;
    for (int kc = 0; kc < 8; kc++) {
        short8 a0 = *(const short8*)(Zg + (size_t)(rb + lm) * LAT + kc * 32 + q * 8);
        short8 a1 = *(const short8*)(Zg + (size_t)(rb + 16 + lm) * LAT + kc * 32 + q * 8);
        #pragma unroll
        for (int nt = 0; nt < 8; nt++) {
            int n = colbase + nt * 16 + lm;
            short8 bf = *(const short8*)(wb1 + (size_t)n * LAT + kc * 32 + q * 8);
            acc[0][nt] = __builtin_amdgcn_mfma_f32_16x16x32_bf16(a0, bf, acc[0][nt], 0, 0, 0);
            acc[1][nt] = __builtin_amdgcn_mfma_f32_16x16x32_bf16(a1, bf, acc[1][nt], 0, 0, 0);
        }
    }
    #pragma unroll
    for (int mt = 0; mt < 2; mt++)
        #pragma unroll
        for (int nt = 0; nt < 8; nt++) {
            int col = colbase + nt * 16 + lm;
            float bias = b1[col];
            #pragma unroll
            for (int i = 0; i < 4; i++) {
                int row = mt * 16 + q * 4 + i;
                hbuf[hswz(row, col)] = f2bf(fmaxf(acc[mt][nt][i] + bias, 0.f));
            }
        }
    __syncthreads();

    const uint16_t* wbs[3] = {wb2, wb3, wb4};
    const float*    bbs[3] = {b2, b3, b4};
    for (int ll = 0; ll < 3; ll++) {
        const uint16_t* wb = wbs[ll];
        const float* bb = bbs[ll];
        #pragma unroll
        for (int mt = 0; mt < 2; mt++)
            #pragma unroll
            for (int nt = 0; nt < 8; nt++) acc[mt][nt] = zero;
        for (int kc = 0; kc < 32; kc++) {
            int g = ((kc * 4 + q) ^ (lm & 7)) << 3;
            short8 a0 = *(const short8*)(hbuf + lm * 1024 + g);
            short8 a1 = *(const short8*)(hbuf + (16 + lm) * 1024 + g);
            #pragma unroll
            for (int nt = 0; nt < 8; nt++) {
                int n = colbase + nt * 16 + lm;
                short8 bf = *(const short8*)(wb + (size_t)n * HID + kc * 32 + q * 8);
                acc[0][nt] = __builtin_amdgcn_mfma_f32_16x16x32_bf16(a0, bf, acc[0][nt], 0, 0, 0);
                acc[1][nt] = __builtin_amdgcn_mfma_f32_16x16x32_bf16(a1, bf, acc[1][nt], 0, 0, 0);
            }
        }
        __syncthreads();
        #pragma unroll
        for (int mt = 0; mt < 2; mt++)
            #pragma unroll
            for (int nt = 0; nt < 8; nt++) {
                int col = colbase + nt * 16 + lm;
                float bias = bb[col];
                #pragma unroll
                for (int i = 0; i < 4; i++) {
                    int row = mt * 16 + q * 4 + i;
                    hbuf[hswz(row, col)] = f2bf(fmaxf(acc[mt][nt][i] + bias, 0.f));
                }
            }
        __syncthreads();
    }

    if (w < 4) {
        int mt = w >> 1;
        int nb = (w & 1) * 16;
        floatx4 a5 = zero;
        for (int kc = 0; kc < 32; kc++) {
            int g = ((kc * 4 + q) ^ (lm & 7)) << 3;
            short8 a = *(const short8*)(hbuf + (mt * 16 + lm) * 1024 + g);
            short8 bf = *(const short8*)(wb5 + (size_t)(nb + lm) * HID + kc * 32 + q * 8);
            a5 = __builtin_amdgcn_mfma_f32_16x16x32_bf16(a, bf, a5, 0, 0, 0);
        }
        int col = nb + lm;
        float bias = b5[col];
        #pragma unroll
        for (int i = 0; i < 4; i++) {
            int row = mt * 16 + q * 4 + i;
            int r = rb + row;
            int bb_ = r >> 8, tt = r & 255;
            out[(size_t)bb_ * (HOR * OBS) + tt * OBS + col] = a5[i] + bias;
        }
    }
}

// ---------------------------------------------------------------------------
// K3 v8: persistent AR. 8 groups x 32 members, 128 thr (2 waves).
// Per step: DMA z tile -> LDS; L1 from LDS; per h-stage: gbar -> DMA h tile
// -> MFMA vs L2-resident weights; stage5 (m<8): L5 + cell, z' -> MALL.
// ---------------------------------------------------------------------------
__global__ __launch_bounds__(ARTHREADS) void k_ar2(
    const float* __restrict__ zfinal,
    const uint16_t* __restrict__ wb1, const uint16_t* __restrict__ wb2,
    const uint16_t* __restrict__ wb3, const uint16_t* __restrict__ wb4,
    const uint16_t* __restrict__ wb5, const uint16_t* __restrict__ wbc,
    const float* __restrict__ b1g, const float* __restrict__ b2g,
    const float* __restrict__ b3g, const float* __restrict__ b4g,
    const float* __restrict__ b5g, const float* __restrict__ cb,
    uint16_t* __restrict__ hb_all, uint16_t* __restrict__ zb_all,
    unsigned* __restrict__ ctr_all, float* __restrict__ out)
{
    __shared__ alignas(16) uint16_t hstg[16 * 1024];  // 32 KB staged h tile
    __shared__ alignas(16) uint16_t zstg[16 * 256];   // 8 KB staged z tile
    __shared__ alignas(16) uint16_t yscr[16 * 32];    // 1 KB
    const int tid = threadIdx.x;
    const int g = blockIdx.x >> 5, m = blockIdx.x & 31;   // member m -> XCD m%8
    const int w = tid >> 6, L = tid & 63, lm = L & 15, q = L >> 4, lm7 = lm & 7;
    const int colbase = m * 32;
    const int cl = w * 16 + lm;
    const int rb = g * 16;
    uint16_t* hb = hb_all + (size_t)g * (4 * 16 * HID);
    uint16_t* zb = zb_all + (size_t)g * (2 * 16 * LAT);
    unsigned* ctr = ctr_all + g * 32;
    const floatx4 zero = {0.f, 0.f, 0.f, 0.f};

    // member 0: zfinal -> z parity 0 at MALL, pre-swizzled
    if (m == 0) {
        for (int idx = tid; idx < 16 * 256; idx += ARTHREADS) {
            int r = idx >> 8, c = idx & 255;
            astore2(zb + zswz(r, c), f2bf(zfinal[(size_t)(rb + r) * LAT + c]));
        }
    }
    unsigned tgt = 0;
    gbar(ctr, tgt += MEMBERS);

    uint16_t* h1 = hb;
    uint16_t* h2 = hb + 16 * HID;
    uint16_t* h3 = hb + 2 * 16 * HID;
    uint16_t* h4 = hb + 3 * 16 * HID;

    #pragma unroll 1
    for (int t = 0; t < HOR - TTF; t++) {
        uint16_t* zcur = zb + (t & 1) * (16 * 256);
        uint16_t* znext = zb + ((t + 1) & 1) * (16 * 256);

        // ---- stage z tile into LDS (1 RTT), then L1 from LDS
        stage_z(zcur, zstg, w, L);
        __syncthreads();
        {
            floatx4 acc = zero;
            const uint16_t* bb = wb1 + (size_t)(colbase + cl) * LAT + q * 8;
            #pragma unroll
            for (int kc = 0; kc < 8; kc++) {
                int gz = (kc * 4 + q) ^ lm7;
                short8 a = *(const short8*)(zstg + lm * 256 + gz * 8);
                short8 b = *(const short8*)(bb + kc * 32);
                acc = __builtin_amdgcn_mfma_f32_16x16x32_bf16(a, b, acc, 0, 0, 0);
            }
            int col = colbase + cl;
            float bias = b1g[col];
            #pragma unroll
            for (int i = 0; i < 4; i++)
                astore2(h1 + hswz(q * 4 + i, col), f2bf(fmaxf(acc[i] + bias, 0.f)));
        }
        gbar(ctr, tgt += MEMBERS);

        // ---- L2: DMA h1 -> LDS, MFMA vs wb2 (L2-resident)
        stage_h(h1, hstg, w, L);
        __syncthreads();
        {
            floatx4 acc = zero;
            const uint16_t* bb = wb2 + (size_t)(colbase + cl) * HID + q * 8;
            #pragma unroll 8
            for (int kc = 0; kc < 32; kc++) {
                int gh = (kc * 4 + q) ^ lm7;
                short8 a = *(const short8*)(hstg + lm * 1024 + gh * 8);
                short8 b = *(const short8*)(bb + kc * 32);
                acc = __builtin_amdgcn_mfma_f32_16x16x32_bf16(a, b, acc, 0, 0, 0);
            }
            int col = colbase + cl;
            float bias = b2g[col];
            #pragma unroll
            for (int i = 0; i < 4; i++)
                astore2(h2 + hswz(q * 4 + i, col), f2bf(fmaxf(acc[i] + bias, 0.f)));
        }
        gbar(ctr, tgt += MEMBERS);

        // ---- L3
        stage_h(h2, hstg, w, L);
        __syncthreads();
        {
            floatx4 acc = zero;
            const uint16_t* bb = wb3 + (size_t)(colbase + cl) * HID + q * 8;
            #pragma unroll 8
            for (int kc = 0; kc < 32; kc++) {
                int gh = (kc * 4 + q) ^ lm7;
                short8 a = *(const short8*)(hstg + lm * 1024 + gh * 8);
                short8 b = *(const short8*)(bb + kc * 32);
                acc = __builtin_amdgcn_mfma_f32_16x16x32_bf16(a, b, acc, 0, 0, 0);
            }
            int col = colbase + cl;
            float bias = b3g[col];
            #pragma unroll
            for (int i = 0; i < 4; i++)
                astore2(h3 + hswz(q * 4 + i, col), f2bf(fmaxf(acc[i] + bias, 0.f)));
        }
        gbar(ctr, tgt += MEMBERS);

        // ---- L4
        stage_h(h3, hstg, w, L);
        __syncthreads();
        {
            floatx4 acc = zero;
            const uint16_t* bb = wb4 + (size_t)(colbase + cl) * HID + q * 8;
            #pragma unroll 8
            for (int kc = 0; kc < 32; kc++) {
                int gh = (kc * 4 + q) ^ lm7;
                short8 a = *(const short8*)(hstg + lm * 1024 + gh * 8);
                short8 b = *(const short8*)(bb + kc * 32);
                acc = __builtin_amdgcn_mfma_f32_16x16x32_bf16(a, b, acc, 0, 0, 0);
            }
            int col = colbase + cl;
            float bias = b4g[col];
            #pragma unroll
            for (int i = 0; i < 4; i++)
                astore2(h4 + hswz(q * 4 + i, col), f2bf(fmaxf(acc[i] + bias, 0.f)));
        }
        gbar(ctr, tgt += MEMBERS);

        // ---- stage 5 (members 0..7): DMA h4, L5 redundant + cell slice
        if (m < 8) {
            stage_h(h4, hstg, w, L);
            __syncthreads();
            floatx4 a5 = zero;
            const uint16_t* bb = wb5 + (size_t)cl * HID + q * 8;
            #pragma unroll 8
            for (int kc = 0; kc < 32; kc++) {
                int gh = (kc * 4 + q) ^ lm7;
                short8 a = *(const short8*)(hstg + lm * 1024 + gh * 8);
                short8 b = *(const short8*)(bb + kc * 32);
                a5 = __builtin_amdgcn_mfma_f32_16x16x32_bf16(a, b, a5, 0, 0, 0);
            }
            float bias = b5g[cl];
            float vout[4];
            #pragma unroll
            for (int i = 0; i < 4; i++) {
                float v = a5[i] + bias;
                vout[i] = v;
                yscr[(q * 4 + i) * 32 + cl] = f2bf(v);
            }
            if (m == 0) {
                #pragma unroll
                for (int i = 0; i < 4; i++)
                    out[(size_t)(rb + q * 4 + i) * (HOR * OBS) + (TTF + t) * OBS + cl] = vout[i];
            }
            __syncthreads();
            // cell: z' cols [32m,32m+32), A = [z(LDS) | yh(LDS)], K=288
            floatx4 cc = zero;
            int ccol = m * 32 + cl;
            const uint16_t* bb2 = wbc + (size_t)ccol * 288 + q * 8;
            #pragma unroll
            for (int kc = 0; kc < 9; kc++) {
                short8 a;
                if (kc < 8) {
                    int gz = (kc * 4 + q) ^ lm7;
                    a = *(const short8*)(zstg + lm * 256 + gz * 8);
                } else {
                    a = *(const short8*)(yscr + lm * 32 + q * 8);
                }
                short8 b = *(const short8*)(bb2 + kc * 32);
                cc = __builtin_amdgcn_mfma_f32_16x16x32_bf16(a, b, cc, 0, 0, 0);
            }
            float cbv = cb[ccol];
            #pragma unroll
            for (int i = 0; i < 4; i++)
                astore2(znext + zswz(q * 4 + i, ccol), f2bf(fast_tanh(cc[i] + cbv)));
        }
        gbar(ctr, tgt += MEMBERS);
    }
}

// ---------------------------------------------------------------------------
extern "C" void kernel_launch(void* const* d_in, const int* in_sizes, int n_in,
                              void* d_out, int out_size, void* d_ws, size_t ws_size,
                              hipStream_t stream) {
    (void)in_sizes; (void)n_in; (void)out_size; (void)ws_size;
    const float* y    = (const float*)d_in[0];
    const float* W_ih = (const float*)d_in[2];
    const float* W_hh = (const float*)d_in[3];
    const float* b_ih = (const float*)d_in[4];
    const float* b_hh = (const float*)d_in[5];
    const float* W1   = (const float*)d_in[6];
    const float* b1   = (const float*)d_in[7];
    const float* W2   = (const float*)d_in[8];
    const float* b2   = (const float*)d_in[9];
    const float* W3   = (const float*)d_in[10];
    const float* b3   = (const float*)d_in[11];
    const float* W4   = (const float*)d_in[12];
    const float* b4   = (const float*)d_in[13];
    const float* W5   = (const float*)d_in[14];
    const float* b5   = (const float*)d_in[15];
    float* out = (float*)d_out;
    char* ws = (char*)d_ws;

    uint16_t* WB1  = (uint16_t*)(ws + OFF_WB1);
    uint16_t* WB2  = (uint16_t*)(ws + OFF_WB2);
    uint16_t* WB3  = (uint16_t*)(ws + OFF_WB3);
    uint16_t* WB4  = (uint16_t*)(ws + OFF_WB4);
    uint16_t* WB5  = (uint16_t*)(ws + OFF_WB5);
    float*    CB   = (float*)(ws + OFF_CB);
    uint2*    WHH2 = (uint2*)(ws + OFF_WHH2);
    uint2*    WIH2 = (uint2*)(ws + OFF_WIH2);
    float*    ZF   = (float*)(ws + OFF_ZF);
    uint16_t* Zbuf = (uint16_t*)(ws + OFF_Z);
    uint16_t* WBC  = (uint16_t*)(ws + OFF_WBC);
    uint16_t* HB   = (uint16_t*)(ws + OFF_HB);
    uint16_t* ZB   = (uint16_t*)(ws + OFF_ZB);
    unsigned* CTR  = (unsigned*)(ws + OFF_CTR);

    k_cvt<<<(HID*LAT + 255) / 256, 256, 0, stream>>>(W1, WB1, HID * LAT);
    k_cvt<<<(HID*HID + 255) / 256, 256, 0, stream>>>(W2, WB2, HID * HID);
    k_cvt<<<(HID*HID + 255) / 256, 256, 0, stream>>>(W3, WB3, HID * HID);
    k_cvt<<<(HID*HID + 255) / 256, 256, 0, stream>>>(W4, WB4, HID * HID);
    k_cvt<<<(OBS*HID + 255) / 256, 256, 0, stream>>>(W5, WB5, OBS * HID);
    k_cb<<<1, 256, 0, stream>>>(b_ih, b_hh, CB);
    k_pack<<<64, 256, 0, stream>>>(W_hh, WHH2, LAT);
    k_pack<<<8, 256, 0, stream>>>(W_ih, WIH2, OBS);
    k_packc<<<256, 256, 0, stream>>>(W_hh, W_ih, WBC);
    hipMemsetAsync(CTR, 0, GROUPS * 128, stream);

    k_rnn_tf<<<BATCH, 256, 0, stream>>>(y, WHH2, WIH2, CB, Zbuf, ZF);

    k_psi_bulk<<<(BATCH * TTF) / 32, 512, 0, stream>>>(
        Zbuf, WB1, WB2, WB3, WB4, WB5, b1, b2, b3, b4, b5, out);

    // Cooperative launch preferred (guaranteed co-residency); on ANY error
    // (R4/R5/R7 died on silent rejection) fall back to a plain launch —
    // 256 blocks at 1+/CU on 256 CUs are co-resident in practice.
    void* args[] = {
        (void*)&ZF, (void*)&WB1, (void*)&WB2, (void*)&WB3, (void*)&WB4,
        (void*)&WB5, (void*)&WBC, (void*)&b1, (void*)&b2, (void*)&b3,
        (void*)&b4, (void*)&b5, (void*)&CB, (void*)&HB, (void*)&ZB,
        (void*)&CTR, (void*)&out
    };
    hipError_t ce = hipLaunchCooperativeKernel((const void*)k_ar2,
                                               dim3(ARBLOCKS), dim3(ARTHREADS),
                                               args, 0, stream);
    if (ce != hipSuccess) {
        (void)hipGetLastError();   // clear sticky error
        k_ar2<<<dim3(ARBLOCKS), dim3(ARTHREADS), 0, stream>>>(
            ZF, WB1, WB2, WB3, WB4, WB5, WBC, b1, b2, b3, b4, b5, CB,
            HB, ZB, CTR, out);
    }
}